// Round 17
// baseline (136.216 us; speedup 1.0000x reference)
//
#include <hip/hip_runtime.h>
#include <stdint.h>

#define BN_EPS 1e-3f

constexpr int Bn = 32, H = 56, Wd = 56, C = 256;
constexpr int NSLOT = 232;          // 4 staged input rows * 58 cols (w/ halo)
constexpr int SSTRIDE = 272;        // 256B data + 16B pad -> 4-bank slot shift
typedef int v4i __attribute__((ext_vector_type(4)));

__device__ __forceinline__ int imax(int a, int b) { return a > b ? a : b; }

// ---------------------------------------------------------------------------
// sign(x) -> i8 {+1,-1}
__global__ __launch_bounds__(256) void k_sign_x(const float* __restrict__ x,
                                                int8_t* __restrict__ xs, int n4) {
  int i = blockIdx.x * 256 + threadIdx.x;
  if (i >= n4) return;
  float4 v = ((const float4*)x)[i];
  char4 s;
  s.x = v.x >= 0.f ? 1 : -1;
  s.y = v.y >= 0.f ? 1 : -1;
  s.z = v.z >= 0.f ? 1 : -1;
  s.w = v.w >= 0.f ? 1 : -1;
  ((char4*)xs)[i] = s;
}

// ---------------------------------------------------------------------------
// Fragment-contiguous weights (verified R12 layout):
// wT2 bytes [f = (tap*4+icq)*16 + ocg][l = grp*16+lid][bb 0..15]
//   = sign(w[tap][ic = icq*64 + grp*16 + bb][oc = ocg*16 + lid])
__global__ __launch_bounds__(256) void k_sign_wT2(const float* __restrict__ w,
                                                  uint32_t* __restrict__ wt) {
  int u = blockIdx.x * 256 + threadIdx.x;   // 0..147455
  int f = u >> 8, r = u & 255;
  int l = r >> 2, w4 = r & 3;
  int grp = l >> 4, lid = l & 15;
  int tap = f >> 6, icq = (f >> 4) & 3, ocg = f & 15;
  int oc = ocg * 16 + lid;
  uint32_t pk = 0;
#pragma unroll
  for (int j = 0; j < 4; ++j) {
    int ic = icq * 64 + grp * 16 + w4 * 4 + j;
    float v = w[((size_t)(tap * 256 + ic)) * 256 + oc];
    pk |= (v >= 0.f ? 0x01u : 0xFFu) << (8 * j);
  }
  wt[u] = pk;
}

// compile-time A byte offset for K-step s (tap = s>>2, icq = s&3)
__device__ constexpr int aoff(int s) {
  const int tap = s >> 2, icq = s & 3;
  const int ky = tap / 3, kx = tap - 3 * ky;
  return (ky * 58 + kx) * SSTRIDE + icq * 64;
}

// ---------------------------------------------------------------------------
// Per-wave GEMM body. Wave = ALL 7 m-subtiles x 2 n-subtiles (N=32 slice).
// A in LDS with PAD-STRIDE slots (272B): addresses are linear, the fully
// unrolled 36-step loop reads A purely via ds imm offsets on 7 base regs
// (zero K-loop VALU for A). B: 2 coalesced 1KB frag loads/step, reg dbuf.
template <int MODE>
__device__ __forceinline__ void conv_body(
    const int8_t* As, const int8_t* __restrict__ wT2, int wn, int lane,
    const float* __restrict__ beta, const float* __restrict__ mean,
    const float* __restrict__ var, int8_t* __restrict__ hs,
    float* __restrict__ outp, int b, int rp)
{
  const int grp = lane >> 4, lid = lane & 15;
  const int wbase = wn * 32;

  // 7 per-lane A base pointers (computed once)
  const int8_t* qb[7];
#pragma unroll
  for (int ms = 0; ms < 7; ++ms) {
    const int m = ms * 16 + lid;
    const int sb = (m & 1) * 58 + (m >> 1);
    qb[ms] = As + sb * SSTRIDE + (grp << 4);
  }

  const int8_t* bq = wT2 + (size_t)wn * 2048 + (size_t)lane * 16;

  v4i acc[7][2];
#pragma unroll
  for (int i = 0; i < 7; ++i)
#pragma unroll
    for (int j = 0; j < 2; ++j) acc[i][j] = (v4i){0, 0, 0, 0};

  v4i bf[2][2];
  bf[0][0] = *(const v4i*)(bq);
  bf[0][1] = *(const v4i*)(bq + 1024);
  bq += 16384;

#pragma unroll
  for (int s = 0; s < 36; ++s) {
    const int pb = s & 1;
    if (s + 1 < 36) {                  // prefetch next step's B fragments
      bf[pb ^ 1][0] = *(const v4i*)(bq);
      bf[pb ^ 1][1] = *(const v4i*)(bq + 1024);
      bq += 16384;
    }
    v4i af[7];
#pragma unroll
    for (int ms = 0; ms < 7; ++ms)
      af[ms] = *(const v4i*)(qb[ms] + aoff(s));   // imm-offset ds_read
    __builtin_amdgcn_s_setprio(1);
#pragma unroll
    for (int ms = 0; ms < 7; ++ms)
#pragma unroll
      for (int ns = 0; ns < 2; ++ns)
        acc[ms][ns] = __builtin_amdgcn_mfma_i32_16x16x64_i8(
            af[ms], bf[pb][ns], acc[ms][ns], 0, 0, 0);
    __builtin_amdgcn_s_setprio(0);
  }

  const int rA = rp * 2;
  if (MODE == 0) {
    // BN1 + sign -> hs (standard NHWC i8)
#pragma unroll
    for (int ns = 0; ns < 2; ++ns) {
      const int oc = wbase + ns * 16 + lid;
      const float mu = mean[oc], rs = rsqrtf(var[oc] + BN_EPS), be = beta[oc];
#pragma unroll
      for (int ms = 0; ms < 7; ++ms)
#pragma unroll
        for (int q = 0; q < 4; ++q) {
          const int m = ms * 16 + grp * 4 + q;
          const int lr = m & 1, col = m >> 1;
          const float bnv = ((float)acc[ms][ns][q] - mu) * rs + be;
          hs[(((size_t)(b * 56 + rA + lr)) * 56 + col) * 256 + oc] =
              bnv >= 0.f ? (int8_t)1 : (int8_t)-1;
        }
    }
  } else {
    // maxpool (lane-local q-quad) + BN2 -> f32
#pragma unroll
    for (int ns = 0; ns < 2; ++ns) {
      const int oc = wbase + ns * 16 + lid;
      const float mu = mean[oc], rs = rsqrtf(var[oc] + BN_EPS), be = beta[oc];
#pragma unroll
      for (int ms = 0; ms < 7; ++ms) {
        const int mx = imax(imax(acc[ms][ns][0], acc[ms][ns][1]),
                            imax(acc[ms][ns][2], acc[ms][ns][3]));
        const int j = ms * 4 + grp;   // pooled col 0..27
        outp[(((size_t)(b * 28 + rp)) * 28 + j) * 256 + oc] =
            ((float)mx - mu) * rs + be;
      }
    }
  }
}

// ---------------------------------------------------------------------------
// 8 waves, each = N=32 slice x all of M=112. 512 threads, 4 waves/EU.
template <int MODE>
__global__ __launch_bounds__(512, 4) void k_conv(
    const int8_t* __restrict__ src, const int8_t* __restrict__ wT2,
    const float* __restrict__ beta, const float* __restrict__ mean,
    const float* __restrict__ var,
    int8_t* __restrict__ hs, float* __restrict__ outp)
{
  const int t = threadIdx.x;
  const int rp = blockIdx.x;          // row pair 0..27
  const int b = blockIdx.y;
  const int rr0 = rp * 2;

  __shared__ __align__(16) int8_t As[NSLOT * SSTRIDE];   // 63104 B

  // Stage A once: slot s = lr*58+colst, chunk c; linear pad-stride layout.
  for (int i = t; i < NSLOT * 16; i += 512) {
    const int s = i >> 4, c = i & 15;
    const int lr = s / 58, colst = s - lr * 58;
    const int sr = rr0 + lr - 1, sc = colst - 1;
    uint4 v;
    v.x = v.y = v.z = v.w = 0u;
    if ((unsigned)sr < 56u && (unsigned)sc < 56u)
      v = *(const uint4*)(src + (((size_t)(b * 56 + sr)) * 56 + sc) * 256 + c * 16);
    *(uint4*)(As + s * SSTRIDE + c * 16) = v;
  }
  __syncthreads();

  const int lane = t & 63;
  const int wn = t >> 6;              // 0..7
  conv_body<MODE>(As, wT2, wn, lane, beta, mean, var, hs, outp, b, rp);
}

// ---------------------------------------------------------------------------
extern "C" void kernel_launch(void* const* d_in, const int* in_sizes, int n_in,
                              void* d_out, int out_size, void* d_ws, size_t ws_size,
                              hipStream_t stream) {
  const float* x     = (const float*)d_in[0];
  const float* w1    = (const float*)d_in[1];
  const float* beta1 = (const float*)d_in[2];
  const float* mean1 = (const float*)d_in[3];
  const float* var1  = (const float*)d_in[4];
  const float* w2    = (const float*)d_in[5];
  const float* beta2 = (const float*)d_in[6];
  const float* mean2 = (const float*)d_in[7];
  const float* var2  = (const float*)d_in[8];
  float* out = (float*)d_out;

  const size_t NPIX = (size_t)Bn * H * Wd * C;  // 25690112
  int8_t* xs  = (int8_t*)d_ws;
  int8_t* hs  = xs + NPIX;
  int8_t* w1t = hs + NPIX;
  int8_t* w2t = w1t + 589824;

  k_sign_x<<<dim3((int)(NPIX / 4 / 256)), 256, 0, stream>>>(x, xs, (int)(NPIX / 4));
  k_sign_wT2<<<dim3(576), 256, 0, stream>>>(w1, (uint32_t*)w1t);
  k_sign_wT2<<<dim3(576), 256, 0, stream>>>(w2, (uint32_t*)w2t);
  k_conv<0><<<dim3(28, Bn), 512, 0, stream>>>(xs, w1t, beta1, mean1, var1, hs, nullptr);
  k_conv<1><<<dim3(28, Bn), 512, 0, stream>>>(hs, w2t, beta2, mean2, var2, nullptr, out);
}